// Round 1
// baseline (535.524 us; speedup 1.0000x reference)
//
#include <hip/hip_runtime.h>
#include <math.h>

// AdaBoost fused inference, v2: barrier-free streaming MFMA.
//   logits = x @ W^T + b   [N=131072, E=256], F=512; pred = (logit > 0)
//   out = sign( sum_e trunc(alpha_e) * pred_e ), only cols with trunc(alpha)!=0 matter.
//
// Changes vs v1 (495 us): the k-loop no longer stages x/W through LDS with
// 2 barriers per k-step (compiler drains vmcnt(0) at every s_barrier -> fully
// latency-bound, MfmaUtil 5%, HBM 8%). Instead:
//   - A-fragments (x) are loaded straight from global (2x float4 per lane,
//     lane l&15 = row, quad*8 = k offset -> 16 rows x 128 B coalesced per wave)
//     and split to bf16 hi/lo in registers.
//   - B-fragments (W) are pre-split to bf16 hi/lo ONCE by a small pre-kernel
//     into d_ws (L2-resident, 512 KB), loaded as ready 16 B bf16x8 fragments.
//   - Main k-loop: no LDS, no __syncthreads, 14 independent loads in flight.
//
// Numerics identical to v1: fp32 -> bf16 two-term split (RNE), 3-MFMA
// (xh*wh + xl*wh + xh*wl), |logit| < TAU re-decided with exact fp64 dot.

#define F_DIM  512
#define BM     128      // rows per block (4 waves x 32 rows)
#define BK     32       // k per MFMA step
#define NTMAX  8        // 16-col MFMA tiles per pass (128 cols)
#define WSLOTS 256
#define TAU    1e-3f

typedef float f32x4  __attribute__((ext_vector_type(4)));
typedef short bf16x8 __attribute__((ext_vector_type(8)));
typedef unsigned short u16x4 __attribute__((ext_vector_type(4)));

__device__ inline unsigned short bf16_rne(float v) {
    unsigned u = __float_as_uint(v);
    u += 0x7FFFu + ((u >> 16) & 1u);
    return (unsigned short)(u >> 16);
}
__device__ inline float bf16_to_f32(unsigned short h) {
    return __uint_as_float(((unsigned)h) << 16);
}

// split 8 floats (a[0..3], b[0..3]) into bf16 hi/lo fragments
__device__ inline void cvt8(const f32x4 a, const f32x4 b, bf16x8& hi, bf16x8& lo) {
    #pragma unroll
    for (int j = 0; j < 4; ++j) {
        const float v0 = a[j], v1 = b[j];
        const unsigned short h0 = bf16_rne(v0);
        const unsigned short h1 = bf16_rne(v1);
        hi[j]     = (short)h0;
        hi[j + 4] = (short)h1;
        lo[j]     = (short)bf16_rne(v0 - bf16_to_f32(h0));
        lo[j + 4] = (short)bf16_rne(v1 - bf16_to_f32(h1));
    }
}

__device__ __attribute__((noinline)) bool exact_pred(const float* __restrict__ xr,
                                                     const float* __restrict__ wr,
                                                     float bv) {
    double s0 = 0.0, s1 = 0.0, s2 = 0.0, s3 = 0.0;
    for (int k = 0; k < F_DIM; k += 4) {
        s0 = fma((double)xr[k + 0], (double)wr[k + 0], s0);
        s1 = fma((double)xr[k + 1], (double)wr[k + 1], s1);
        s2 = fma((double)xr[k + 2], (double)wr[k + 2], s2);
        s3 = fma((double)xr[k + 3], (double)wr[k + 3], s3);
    }
    double s = ((s0 + s1) + (s2 + s3)) + (double)bv;
    return s > 0.0;
}

// ---------------- pre-kernel: compact active estimators, split W -> bf16 hi/lo in ws
__global__ __launch_bounds__(256)
void ada_prep(const float* __restrict__ W, const float* __restrict__ alphas,
              unsigned short* __restrict__ whi, unsigned short* __restrict__ wlo) {
    __shared__ int se[WSLOTS];
    __shared__ int wcnt[4];
    const int tid = threadIdx.x;

    se[tid] = 0;
    __syncthreads();
    const float t = truncf(alphas[tid]);
    const bool flag = (t != 0.0f);
    const unsigned long long m64 = __ballot(flag);
    const int lane = tid & 63, wvi = tid >> 6;
    if (lane == 0) wcnt[wvi] = __popcll(m64);
    __syncthreads();
    int off = 0;
    #pragma unroll
    for (int w = 0; w < 4; ++w) if (w < wvi) off += wcnt[w];
    if (flag) se[off + __popcll(m64 & ((1ull << lane) - 1ull))] = tid;
    __syncthreads();

    // convert all 256 slots (slots >= M point at W[0]: valid, never used downstream)
    const int gstride = gridDim.x * blockDim.x;
    for (int job = blockIdx.x * blockDim.x + tid; job < WSLOTS * (F_DIM / 4); job += gstride) {
        const int col = job >> 7;              // F_DIM/4 = 128 jobs per column
        const int k4  = (job & 127) << 2;
        const f32x4 v = *(const f32x4*)(W + (size_t)se[col] * F_DIM + k4);
        u16x4 hv, lv;
        #pragma unroll
        for (int j = 0; j < 4; ++j) {
            const unsigned short h = bf16_rne(v[j]);
            hv[j] = h;
            lv[j] = bf16_rne(v[j] - bf16_to_f32(h));
        }
        *(u16x4*)(whi + (size_t)col * F_DIM + k4) = hv;
        *(u16x4*)(wlo + (size_t)col * F_DIM + k4) = lv;
    }
}

// ---------------- main kernel: barrier-free streaming GEMM + vote
__global__ __launch_bounds__(256, 3)
void ada_mfma2(const float* __restrict__ x, const float* __restrict__ W,
               const float* __restrict__ bias, const float* __restrict__ alphas,
               const unsigned short* __restrict__ whi, const unsigned short* __restrict__ wlo,
               float* __restrict__ out) {
    __shared__ int   se[WSLOTS];
    __shared__ float st[WSLOTS];
    __shared__ float sb[WSLOTS];
    __shared__ int   wcnt[4];

    const int tid = threadIdx.x;
    const int n0  = blockIdx.x * BM;

    // ---- compaction of active estimators (verified deterministic ballot prefix-sum)
    se[tid] = 0; st[tid] = 0.0f; sb[tid] = 0.0f;
    __syncthreads();
    const float t = truncf(alphas[tid]);
    const bool flag = (t != 0.0f);
    const unsigned long long m64 = __ballot(flag);
    const int lane = tid & 63, wvi = tid >> 6;
    if (lane == 0) wcnt[wvi] = __popcll(m64);
    __syncthreads();
    int off = 0;
    #pragma unroll
    for (int w = 0; w < 4; ++w) if (w < wvi) off += wcnt[w];
    const int M = wcnt[0] + wcnt[1] + wcnt[2] + wcnt[3];
    if (flag) {
        const int slot = off + __popcll(m64 & ((1ull << lane) - 1ull));
        se[slot] = tid; st[slot] = t; sb[slot] = bias[tid];
    }
    __syncthreads();   // last barrier in the kernel

    // ---- ids
    const int quad = (tid >> 4) & 3;    // lane>>4 within wave
    const int l15  = tid & 15;
    const int rw   = (tid >> 6) * 32;   // wave's row base within block

    // per-lane x row pointers (mt=0/1), already offset by quad*8 in k
    const float* xp0 = x + (size_t)(n0 + rw + l15) * F_DIM + quad * 8;
    const float* xp1 = xp0 + (size_t)16 * F_DIM;

    int part[2][4];
    #pragma unroll
    for (int mt = 0; mt < 2; ++mt)
        #pragma unroll
        for (int r = 0; r < 4; ++r) part[mt][r] = 0;

    for (int cb = 0; cb < M; cb += 128) {
        const int Mrem = M - cb;
        const int NT   = (Mrem + 15) >> 4 < NTMAX ? (Mrem + 15) >> 4 : NTMAX;

        // W fragment base for this pass: col = cb + nt*16 + l15, k offset quad*8
        const unsigned short* wph = whi + (size_t)(cb + l15) * F_DIM + quad * 8;
        const unsigned short* wpl = wlo + (size_t)(cb + l15) * F_DIM + quad * 8;

        f32x4 acc[2][NTMAX];
        #pragma unroll
        for (int mt = 0; mt < 2; ++mt)
            #pragma unroll
            for (int nt = 0; nt < NTMAX; ++nt)
                acc[mt][nt] = (f32x4){0.0f, 0.0f, 0.0f, 0.0f};

        // prefetch k0 = 0
        f32x4 xv0 = *(const f32x4*)(xp0);
        f32x4 xv1 = *(const f32x4*)(xp0 + 4);
        f32x4 xv2 = *(const f32x4*)(xp1);
        f32x4 xv3 = *(const f32x4*)(xp1 + 4);

        for (int k0 = 0; k0 < F_DIM; k0 += BK) {
            // convert current x fragments to bf16 hi/lo in registers
            bf16x8 ah[2], al[2];
            cvt8(xv0, xv1, ah[0], al[0]);
            cvt8(xv2, xv3, ah[1], al[1]);

            // prefetch next k-step (independent of everything below)
            const int kn = k0 + BK;
            if (kn < F_DIM) {
                xv0 = *(const f32x4*)(xp0 + kn);
                xv1 = *(const f32x4*)(xp0 + kn + 4);
                xv2 = *(const f32x4*)(xp1 + kn);
                xv3 = *(const f32x4*)(xp1 + kn + 4);
            }

            #pragma unroll
            for (int nt = 0; nt < NTMAX; ++nt) {
                if (nt < NT) {
                    const bf16x8 bh = *(const bf16x8*)(wph + (size_t)nt * 16 * F_DIM + k0);
                    const bf16x8 bl = *(const bf16x8*)(wpl + (size_t)nt * 16 * F_DIM + k0);
                    #pragma unroll
                    for (int mt = 0; mt < 2; ++mt) {
                        acc[mt][nt] = __builtin_amdgcn_mfma_f32_16x16x32_bf16(ah[mt], bh, acc[mt][nt], 0, 0, 0);
                        acc[mt][nt] = __builtin_amdgcn_mfma_f32_16x16x32_bf16(al[mt], bh, acc[mt][nt], 0, 0, 0);
                        acc[mt][nt] = __builtin_amdgcn_mfma_f32_16x16x32_bf16(ah[mt], bl, acc[mt][nt], 0, 0, 0);
                    }
                }
            }
        }

        // ---- epilogue for this col pass: threshold + integer vote (C/D: col=l15, row=quad*4+reg)
        #pragma unroll
        for (int nt = 0; nt < NTMAX; ++nt) {
            if (nt < NT) {
                const int col = cb + nt * 16 + l15;
                const float tv = st[col];
                if (tv != 0.0f) {
                    const float bv = sb[col];
                    const int it = (int)tv;
                    #pragma unroll
                    for (int mt = 0; mt < 2; ++mt) {
                        #pragma unroll
                        for (int r = 0; r < 4; ++r) {
                            const float logit = acc[mt][nt][r] + bv;
                            bool pred = (logit > 0.0f);
                            if (fabsf(logit) < TAU) {
                                const int row = rw + mt * 16 + quad * 4 + r;
                                pred = exact_pred(x + (size_t)(n0 + row) * F_DIM,
                                                  W + (size_t)se[col] * F_DIM, bv);
                            }
                            if (pred) part[mt][r] += it;
                        }
                    }
                }
            }
        }
    }

    // ---- reduce the 16 col-lanes of each quad, then store 4 consecutive rows as float4
    #pragma unroll
    for (int mt = 0; mt < 2; ++mt) {
        #pragma unroll
        for (int r = 0; r < 4; ++r) {
            int v = part[mt][r];
            v += __shfl_xor(v, 1);
            v += __shfl_xor(v, 2);
            v += __shfl_xor(v, 4);
            v += __shfl_xor(v, 8);
            part[mt][r] = v;
        }
    }
    if (l15 == 0) {
        #pragma unroll
        for (int mt = 0; mt < 2; ++mt) {
            float4 o;
            o.x = (part[mt][0] > 0) ? 1.0f : (part[mt][0] < 0 ? -1.0f : 0.0f);
            o.y = (part[mt][1] > 0) ? 1.0f : (part[mt][1] < 0 ? -1.0f : 0.0f);
            o.z = (part[mt][2] > 0) ? 1.0f : (part[mt][2] < 0 ? -1.0f : 0.0f);
            o.w = (part[mt][3] > 0) ? 1.0f : (part[mt][3] < 0 ? -1.0f : 0.0f);
            *(float4*)(out + n0 + rw + mt * 16 + quad * 4) = o;
        }
    }
}

extern "C" void kernel_launch(void* const* d_in, const int* in_sizes, int n_in,
                              void* d_out, int out_size, void* d_ws, size_t ws_size,
                              hipStream_t stream) {
    const float* x      = (const float*)d_in[0];   // [N, 512]
    const float* W      = (const float*)d_in[1];   // [256, 512]
    const float* bias   = (const float*)d_in[2];   // [256]
    const float* alphas = (const float*)d_in[3];   // [256]
    float* out = (float*)d_out;                    // [N]

    const int n = in_sizes[0] / F_DIM;             // 131072
    const int nblocks = n / BM;                    // 1024

    // ws: whi [256][512] ushort, wlo [256][512] ushort  (512 KB total)
    unsigned short* whi = (unsigned short*)d_ws;
    unsigned short* wlo = whi + (size_t)WSLOTS * F_DIM;

    ada_prep<<<dim3(64), dim3(256), 0, stream>>>(W, alphas, whi, wlo);
    ada_mfma2<<<dim3(nblocks), dim3(256), 0, stream>>>(x, W, bias, alphas, whi, wlo, out);
}